// Round 15
// baseline (1769.128 us; speedup 1.0000x reference)
//
#include <hip/hip_runtime.h>
#include <math.h>

#pragma clang fp contract(off)   // no implicit fusion; FMA only where ref has it

// Problem constants (fixed by the reference)
#define BB   8
#define NN   16384
#define FF   32
#define SS   2048
#define KK   32
#define OUTC 128

// Filter margin. Requirement: EPS2 >= 2*eps_max; eps_max = Sigma|a_k b_k|*2^-8
// ~0.08 typical / ~0.17 at +5sigma -> 2*eps ~ 0.33 worst. 1.5 = 4.5x slack,
// and keeps the post-compaction keep-set (~41) far below the 64-slot cap.
#define EPS2 1.5f

typedef __attribute__((ext_vector_type(8))) short short8x;
typedef __attribute__((ext_vector_type(4))) float float4x;

// force a value into uniform (SGPR) representation — ONLY for wave-uniform-address reads
__device__ __forceinline__ float uni(float v) {
    return __uint_as_float(__builtin_amdgcn_readfirstlane(__float_as_uint(v)));
}
__device__ __forceinline__ int uni_i(int v) { return __builtin_amdgcn_readfirstlane(v); }

// float -> bf16 round-to-nearest-even
__device__ __forceinline__ unsigned short f2bf(float f) {
    unsigned u = __float_as_uint(f);
    unsigned r = (u + 0x7fffu + ((u >> 16) & 1u)) >> 16;
    return (unsigned short)r;
}

// ---------------------------------------------------------------------------
// Reference-bit-exact fp32 helpers (validated R0-R7):
// x_sq / s_sq: numpy pairwise_sum scalar 8-accumulator block (n=32, no FMA)
__device__ __forceinline__ float np_sumsq32(const float* a) {
    float r[8];
#pragma unroll
    for (int j = 0; j < 8; j++) r[j] = a[j] * a[j];
#pragma unroll
    for (int t = 1; t < 4; t++) {
#pragma unroll
        for (int j = 0; j < 8; j++) {
            float e = a[8 * t + j] * a[8 * t + j];
            r[j] = r[j] + e;
        }
    }
    return ((r[0] + r[1]) + (r[2] + r[3])) + ((r[4] + r[5]) + (r[6] + r[7]));
}

// ---------------------------------------------------------------------------
// K1a: x_sq[b,n] = ref-order sum_f x^2;  also emit bf16 copy of x (MFMA filter).
// x16 ALIASES the h2 region of d_ws; topk (its only reader) runs before mlp.
__global__ __launch_bounds__(256) void xsq_kernel(const float* __restrict__ x,
                                                  float* __restrict__ xsq,
                                                  unsigned short* __restrict__ x16) {
    int gid = blockIdx.x * 256 + threadIdx.x;      // < B*N
    const float4* r = (const float4*)(x + (size_t)gid * FF);
    float a[32];
#pragma unroll
    for (int j = 0; j < 8; j++) {
        float4 v = r[j];
        a[4 * j] = v.x; a[4 * j + 1] = v.y; a[4 * j + 2] = v.z; a[4 * j + 3] = v.w;
    }
    xsq[gid] = np_sumsq32(a);
    unsigned short h[32];
#pragma unroll
    for (int k = 0; k < 32; k++) h[k] = f2bf(a[k]);
#pragma unroll
    for (int j = 0; j < 4; j++)
        *(uint4*)(x16 + (size_t)gid * FF + j * 8) = *(const uint4*)&h[j * 8];
}

// ---------------------------------------------------------------------------
// K1b: gather sampled features (row-major [B,S,F]) + ref-order s_sq
__global__ __launch_bounds__(256) void gather_kernel(const float* __restrict__ x,
                                                     const int* __restrict__ sidx,
                                                     float* __restrict__ sampled,
                                                     float* __restrict__ ssq) {
    int gid = blockIdx.x * 256 + threadIdx.x;      // < B*S
    int b = gid >> 11;
    int idx = sidx[gid];
    const float4* r = (const float4*)(x + ((size_t)b * NN + idx) * FF);
    float4* wo = (float4*)(sampled + (size_t)gid * FF);
    float a[32];
#pragma unroll
    for (int j = 0; j < 8; j++) {
        float4 v = r[j];
        a[4 * j] = v.x; a[4 * j + 1] = v.y; a[4 * j + 2] = v.z; a[4 * j + 3] = v.w;
        wo[j] = v;
    }
    ssq[gid] = np_sumsq32(a);
}

// ---------------------------------------------------------------------------
// K1c: sampled [B,S,F] -> output sampled_batch [B,F,S] (transpose via LDS)
__global__ __launch_bounds__(256) void transpose_kernel(const float* __restrict__ sampled,
                                                        float* __restrict__ out_samp) {
    __shared__ float tile[32][65];
    int b = blockIdx.x >> 5, sg = blockIdx.x & 31;
    int s0 = sg * 64;
    int tid = threadIdx.x;
    int f = tid & 31, si = tid >> 5;               // si in 0..7
#pragma unroll
    for (int r = 0; r < 8; r++) {
        int s = r * 8 + si;
        tile[f][s] = sampled[((size_t)b * SS + s0 + s) * FF + f];
    }
    __syncthreads();
#pragma unroll
    for (int r = 0; r < 8; r++) {
        int flat = r * 256 + tid;
        int fo = flat >> 6, sw = flat & 63;
        out_samp[((size_t)b * FF + fo) * SS + s0 + sw] = tile[fo][sw];
    }
}

// ---------------------------------------------------------------------------
// K2: per-point MLP, h2[b,n,:] = W2 @ relu(W1 @ x + b1) + b2  (fp32, VALU)
__global__ __launch_bounds__(256) void mlp_kernel(const float* __restrict__ x,
                                                  const float* __restrict__ W1,
                                                  const float* __restrict__ b1,
                                                  const float* __restrict__ W2,
                                                  const float* __restrict__ b2,
                                                  float* __restrict__ h2) {
    __shared__ float xs[64][36];          // padded
    __shared__ float hs[8512];            // h1t [128][65] then reused as h2s [64][133]
    int tid = threadIdx.x, lane = tid & 63;
    int wu = __builtin_amdgcn_readfirstlane(tid >> 6);
    size_t p0 = (size_t)blockIdx.x * 64;

    for (int i = tid; i < 64 * 8; i += 256) {
        int row = i >> 3, seg = i & 7;
        *(float4*)&xs[row][seg * 4] = *(const float4*)(x + (p0 + row) * FF + seg * 4);
    }
    __syncthreads();

    float xr[32];
    {
        const float4* r = (const float4*)&xs[lane][0];
#pragma unroll
        for (int j = 0; j < 8; j++) {
            float4 v = r[j];
            xr[4 * j] = v.x; xr[4 * j + 1] = v.y; xr[4 * j + 2] = v.z; xr[4 * j + 3] = v.w;
        }
    }
#pragma unroll 4
    for (int i = 0; i < 32; i++) {
        int o = wu * 32 + i;
        const float4* wr = (const float4*)(W1 + o * FF);
        float a = b1[o];
#pragma unroll
        for (int j = 0; j < 8; j++) {
            float4 v = wr[j];
            a = fmaf(v.x, xr[4 * j], a);     a = fmaf(v.y, xr[4 * j + 1], a);
            a = fmaf(v.z, xr[4 * j + 2], a); a = fmaf(v.w, xr[4 * j + 3], a);
        }
        hs[o * 65 + lane] = fmaxf(a, 0.f);
    }
    __syncthreads();
    float acc[32];
#pragma unroll
    for (int i = 0; i < 32; i++) acc[i] = b2[wu * 32 + i];
    for (int k4 = 0; k4 < 32; k4++) {
        float h0 = hs[(4 * k4 + 0) * 65 + lane];
        float h1v = hs[(4 * k4 + 1) * 65 + lane];
        float h2v = hs[(4 * k4 + 2) * 65 + lane];
        float h3v = hs[(4 * k4 + 3) * 65 + lane];
#pragma unroll
        for (int i = 0; i < 32; i++) {
            const float4 v = *(const float4*)(W2 + (wu * 32 + i) * OUTC + 4 * k4);
            acc[i] = fmaf(v.x, h0, acc[i]);  acc[i] = fmaf(v.y, h1v, acc[i]);
            acc[i] = fmaf(v.z, h2v, acc[i]); acc[i] = fmaf(v.w, h3v, acc[i]);
        }
    }
    __syncthreads();
#pragma unroll 4
    for (int i = 0; i < 32; i++) hs[lane * 133 + wu * 32 + i] = acc[i];
    __syncthreads();
    for (int j = 0; j < 32; j++) {
        int flat = j * 256 + tid;
        int p = flat >> 7, o = flat & 127;
        h2[(p0 + p) * OUTC + o] = hs[p * 133 + o];
    }
}

// ---------------------------------------------------------------------------
// sorting / compaction machinery (validated R7-R12)
__device__ __forceinline__ bool lessp(float da, int ia, float db, int ib) {
    return da < db || (da == db && ia < ib);
}
__device__ __forceinline__ void cswap(float& d, int& i, int j, bool dirAsc, int lane) {
    float od = __shfl_xor(d, j);
    int   oi = __shfl_xor(i, j);
    bool lower = (lane & j) == 0;
    bool oLess = lessp(od, oi, d, i);
    if (oLess == (lower == dirAsc)) { d = od; i = oi; }
}
__device__ __forceinline__ void sort64(float& d, int& i, bool asc, int lane) {
#pragma unroll
    for (int k = 2; k <= 64; k <<= 1) {
        bool ba = (((lane & k) == 0) == asc);
#pragma unroll
        for (int j = k >> 1; j > 0; j >>= 1) cswap(d, i, j, ba, lane);
    }
}
// sort m valid slots (m<=128), keep lowest-64 lex-sorted in [0,64); return 32nd-smallest
__device__ __forceinline__ float wave_compact2(float* bd, int* bi, int m, int lane) {
    float d0 = (lane < m) ? bd[lane] : INFINITY;
    int   i0 = (lane < m) ? bi[lane] : 0x7fffffff;
    float d1 = (lane + 64 < m) ? bd[lane + 64] : INFINITY;
    int   i1 = (lane + 64 < m) ? bi[lane + 64] : 0x7fffffff;
    sort64(d0, i0, true, lane);
    sort64(d1, i1, false, lane);
    bool t = lessp(d1, i1, d0, i0);
    float ld = t ? d1 : d0;
    int   li = t ? i1 : i0;
#pragma unroll
    for (int j = 32; j > 0; j >>= 1) cswap(ld, li, j, true, lane);
    bd[lane] = ld; bi[lane] = li;
    return uni(__shfl(ld, 31));            // broadcast then uniform: OK
}
// approx-domain compaction: keep everything within EPS2 of the 32nd-smallest
__device__ __forceinline__ float compact_keep(float* bd, int* bi, int m, int lane, int* newc) {
    float t32 = wave_compact2(bd, bi, m, lane);
    float thr = t32 + EPS2;
    float ld = bd[lane];                   // sorted ascending
    unsigned long long km = __ballot(ld <= thr);
    int k = __builtin_popcountll(km);      // prefix count (sorted)
    if (k > 64) k = 64;
    *newc = k;
    return thr;
}

// ---------------------------------------------------------------------------
// K3 v9: MFMA-filtered exact top-32.  1 wave/block, 16 queries/block.
// Phase 1: bf16 16x16x32 MFMA approx distances; conservative filter (EPS2).
// Phase 2: ref-bit-exact fp32 rescoring of survivors + stable lex sort.
// R14 bug fixed: taur refresh used readfirstlane on a per-quad LDS address,
// giving quads 1-3 the thresholds of queries 0-3 -> true neighbors dropped.
__global__ __launch_bounds__(64) void topk_kernel(const float* __restrict__ x,
                                                  const unsigned short* __restrict__ x16,
                                                  const float* __restrict__ x_sq,
                                                  const float* __restrict__ sampled,
                                                  const float* __restrict__ s_sq,
                                                  int* __restrict__ nbr) {
    int b = blockIdx.x & 7;                 // XCD-by-batch swizzle (x16 1MB/batch -> L2)
    int qg = blockIdx.x >> 3;               // 0..127
    int qbase = qg * 16;
    int lane = threadIdx.x & 63;
    int c15 = lane & 15, quad = lane >> 4;

    __shared__ float bufd[16][128];
    __shared__ int   bufi[16][128];
    __shared__ int   cnt[16];
    __shared__ float tauL[16];

    const float*          xb   = x    + (size_t)b * NN * FF;
    const unsigned short* xb16 = x16  + (size_t)b * NN * FF;
    const float*          xqb  = x_sq + (size_t)b * NN;

    if (lane < 16) { cnt[lane] = 0; tauL[lane] = INFINITY; }

    // A fragment: query (qbase + c15), k = quad*8..quad*8+7  (bf16 RNE)
    short8x afrag;
    {
        const float* qp = sampled + ((size_t)b * SS + qbase + c15) * FF + quad * 8;
        unsigned short h[8];
#pragma unroll
        for (int j = 0; j < 8; j++) h[j] = f2bf(qp[j]);
        afrag = *(const short8x*)h;
    }
    // ssq for this lane's 4 D-rows: q = quad*4 + r
    float ssqr[4];
#pragma unroll
    for (int r = 0; r < 4; r++) ssqr[r] = s_sq[(size_t)b * SS + qbase + quad * 4 + r];
    float taur[4] = {INFINITY, INFINITY, INFINITY, INFINITY};

    // software-pipelined scan: 1024 tiles of 16 candidates, prefetch depth 4
#define PD 4
    short8x bfr[PD];
    float   xnr[PD];
#pragma unroll
    for (int i = 0; i < PD; i++) {
        int n0 = i * 16;
        bfr[i] = *(const short8x*)(xb16 + (size_t)(n0 + c15) * FF + quad * 8);
        xnr[i] = xqb[n0 + c15];
    }
    for (int tt = 0; tt < NN / 16; tt += PD) {
#pragma unroll
        for (int u = 0; u < PD; u++) {
            int t = tt + u;
            float4x cc = __builtin_amdgcn_mfma_f32_16x16x32_bf16(afrag, bfr[u],
                                                                 (float4x)0.f, 0, 0, 0);
            float xn = xnr[u];
            int n = t * 16 + c15;
            // prefetch tile t+PD into this slot
            if (t + PD < NN / 16) {
                int n0 = (t + PD) * 16;
                bfr[u] = *(const short8x*)(xb16 + (size_t)(n0 + c15) * FF + quad * 8);
                xnr[u] = xqb[n0 + c15];
            }
            float d0 = (ssqr[0] + xn) - (cc[0] + cc[0]);
            float d1 = (ssqr[1] + xn) - (cc[1] + cc[1]);
            float d2 = (ssqr[2] + xn) - (cc[2] + cc[2]);
            float d3 = (ssqr[3] + xn) - (cc[3] + cc[3]);
            bool h0 = d0 <= taur[0], h1 = d1 <= taur[1];
            bool h2v = d2 <= taur[2], h3 = d3 <= taur[3];
            unsigned long long any = __ballot(h0 || h1 || h2v || h3);
            if (any) {                       // wave-uniform
                if (h0) { int p = atomicAdd(&cnt[quad * 4 + 0], 1); if (p < 128) { bufd[quad * 4 + 0][p] = d0; bufi[quad * 4 + 0][p] = n; } }
                if (h1) { int p = atomicAdd(&cnt[quad * 4 + 1], 1); if (p < 128) { bufd[quad * 4 + 1][p] = d1; bufi[quad * 4 + 1][p] = n; } }
                if (h2v){ int p = atomicAdd(&cnt[quad * 4 + 2], 1); if (p < 128) { bufd[quad * 4 + 2][p] = d2; bufi[quad * 4 + 2][p] = n; } }
                if (h3) { int p = atomicAdd(&cnt[quad * 4 + 3], 1); if (p < 128) { bufd[quad * 4 + 3][p] = d3; bufi[quad * 4 + 3][p] = n; } }
                // compaction check (cnt[q]: uniform address -> uni_i OK)
                bool need = false;
#pragma unroll
                for (int q = 0; q < 16; q++) need = need || (uni_i(cnt[q]) > 112);
                if (need) {
                    for (int q = 0; q < 16; q++) {
                        int cq = uni_i(cnt[q]);
                        if (cq > 112) {
                            int nc;
                            float nt = compact_keep(&bufd[q][0], &bufi[q][0],
                                                    cq > 128 ? 128 : cq, lane, &nc);
                            if (lane == 0) { cnt[q] = nc; tauL[q] = nt; }
                        }
                    }
                    // FIX (R14 bug): per-lane LDS read — address differs per quad,
                    // readfirstlane here propagated query 0-3 thresholds to all quads.
#pragma unroll
                    for (int r = 0; r < 4; r++) taur[r] = tauL[quad * 4 + r];
                }
            }
        }
    }
    // Phase 2: exact ref-order rescoring + stable sort, emit top-32
    for (int q = 0; q < 16; q++) {
        int m = uni_i(cnt[q]); if (m > 128) m = 128;
        float ssqq = uni(s_sq[(size_t)b * SS + qbase + q]);
        const float* sqp = sampled + ((size_t)b * SS + qbase + q) * FF;  // uniform
#pragma unroll
        for (int half = 0; half < 2; half++) {
            int slot = lane + half * 64;
            if (slot < m) {
                int idx = bufi[q][slot];
                const float* xr = xb + (size_t)idx * FF;
                float c = 0.f;
#pragma unroll
                for (int k = 0; k < 32; k++) c = fmaf(sqp[k], xr[k], c);   // ref chain
                bufd[q][slot] = (ssqq + xqb[idx]) - (c + c);               // ref combine
            }
        }
        wave_compact2(&bufd[q][0], &bufi[q][0], m, lane);
        if (lane < 32) nbr[((size_t)b * SS + qbase + q) * KK + lane] = bufi[q][lane];
    }
}

// ---------------------------------------------------------------------------
// K4: features_batch[b,o,s] = max_k h2[b, nbr[b,s,k], o]; block=128, 16 s/block
__global__ __launch_bounds__(128) void maxgather_kernel(const float* __restrict__ h2,
                                                        const int* __restrict__ nbr,
                                                        float* __restrict__ out_feat) {
    __shared__ float fs[128][17];
    int b = blockIdx.x & 7;
    int sg = blockIdx.x >> 3;               // 0..127
    int s0 = sg * 16;
    int tid = threadIdx.x;                  // o = tid (0..127)
    for (int si = 0; si < 16; si++) {
        int s = s0 + si;
        const int* row = nbr + ((size_t)b * SS + s) * KK;
        float m = -INFINITY;
#pragma unroll 4
        for (int k = 0; k < KK; k++) {
            int idx = row[k];
            float v = h2[((size_t)b * NN + idx) * OUTC + tid];
            m = fmaxf(m, v);
        }
        fs[tid][si] = m;
    }
    __syncthreads();
#pragma unroll
    for (int j = 0; j < 16; j++) {
        int flat = j * 128 + tid;
        int fo = flat >> 4, sw = flat & 15;
        out_feat[((size_t)b * OUTC + fo) * SS + s0 + sw] = fs[fo][sw];
    }
}

// ---------------------------------------------------------------------------
extern "C" void kernel_launch(void* const* d_in, const int* in_sizes, int n_in,
                              void* d_out, int out_size, void* d_ws, size_t ws_size,
                              hipStream_t stream) {
    const float* x    = (const float*)d_in[0];
    const int*   sidx = (const int*)d_in[1];
    const float* W1   = (const float*)d_in[2];
    const float* b1   = (const float*)d_in[3];
    const float* W2   = (const float*)d_in[4];
    const float* b2   = (const float*)d_in[5];

    float* out_feat = (float*)d_out;                       // [B,128,S]
    float* out_samp = out_feat + (size_t)BB * OUTC * SS;   // [B,32,S]

    // workspace carve-up (68.6 MB, same footprint as the passing R7-R12 rounds):
    // x16 (8 MB, bf16 copy of x) ALIASES the front of h2's 64 MB region —
    // topk (only x16 reader) is launched BEFORE mlp (h2 writer).
    float* h2      = (float*)d_ws;                         // B*N*128 fp32 = 64 MB
    unsigned short* x16 = (unsigned short*)d_ws;           // B*N*F bf16 = 8 MB (alias)
    float* sampled = h2 + (size_t)BB * NN * OUTC;          // B*S*F
    float* xsq     = sampled + (size_t)BB * SS * FF;       // B*N
    float* ssq     = xsq + (size_t)BB * NN;                // B*S
    int*   nbr     = (int*)(ssq + (size_t)BB * SS);        // B*S*K

    xsq_kernel<<<dim3(BB * NN / 256), dim3(256), 0, stream>>>(x, xsq, x16);
    gather_kernel<<<dim3(BB * SS / 256), dim3(256), 0, stream>>>(x, sidx, sampled, ssq);
    topk_kernel<<<dim3(BB * SS / 16), dim3(64), 0, stream>>>(x, x16, xsq, sampled, ssq, nbr);
    transpose_kernel<<<dim3(BB * SS / 64), dim3(256), 0, stream>>>(sampled, out_samp);
    mlp_kernel<<<dim3(BB * NN / 64), dim3(256), 0, stream>>>(x, W1, b1, W2, b2, h2);
    maxgather_kernel<<<dim3(BB * SS / 16), dim3(128), 0, stream>>>(h2, nbr, out_feat);
}